// Round 1
// baseline (797.326 us; speedup 1.0000x reference)
//
#include <hip/hip_runtime.h>
#include <stdint.h>

typedef __bf16 bf16;
typedef __bf16 bf16x4 __attribute__((ext_vector_type(4)));
typedef __bf16 bf16x8 __attribute__((ext_vector_type(8)));
typedef float  f32x4  __attribute__((ext_vector_type(4)));

constexpr int BB = 8;
constexpr int NN = 2048;
constexpr int EE = 768;
constexpr int MM = BB * NN;  // 16384

typedef const __attribute__((address_space(1))) void* as1_cvp;
typedef __attribute__((address_space(3))) void* as3_vp;

static __device__ __forceinline__ void gld16(const void* g, void* l) {
  __builtin_amdgcn_global_load_lds((as1_cvp)g, (as3_vp)l, 16, 0, 0);
}

// ---------------- conversion kernels ----------------
__global__ __launch_bounds__(256) void k_split(const float4* __restrict__ x,
                                               bf16x4* __restrict__ hi,
                                               bf16x4* __restrict__ lo, int n4) {
  int i = blockIdx.x * 256 + threadIdx.x;
  int st = gridDim.x * 256;
  for (; i < n4; i += st) {
    float4 v = x[i];
    bf16x4 h, l;
    h[0] = (bf16)v.x; l[0] = (bf16)(v.x - (float)h[0]);
    h[1] = (bf16)v.y; l[1] = (bf16)(v.y - (float)h[1]);
    h[2] = (bf16)v.z; l[2] = (bf16)(v.z - (float)h[2]);
    h[3] = (bf16)v.w; l[3] = (bf16)(v.w - (float)h[3]);
    hi[i] = h; lo[i] = l;
  }
}

__global__ __launch_bounds__(256) void k_cvt(const float4* __restrict__ x,
                                             bf16x4* __restrict__ y, int n4) {
  int i = blockIdx.x * 256 + threadIdx.x;
  int st = gridDim.x * 256;
  for (; i < n4; i += st) {
    float4 v = x[i];
    bf16x4 h;
    h[0] = (bf16)v.x; h[1] = (bf16)v.y; h[2] = (bf16)v.z; h[3] = (bf16)v.w;
    y[i] = h;
  }
}

// ---------------- transpose: V[b][n][f] -> Vt[b][f][n] ----------------
__global__ __launch_bounds__(256) void k_transpose(const bf16* __restrict__ src,
                                                   bf16* __restrict__ dst) {
  __shared__ __align__(16) bf16 t[64 * 64];
  int b = blockIdx.z;
  int n0 = blockIdx.x * 64, f0 = blockIdx.y * 64;
  int tid = threadIdx.x;
  int r = tid >> 3;        // 0..31
  int cc = tid & 7;        // 16B chunk idx 0..7
  const bf16* s = src + ((size_t)b * NN + n0) * EE + f0;
#pragma unroll
  for (int h = 0; h < 2; h++) {
    int row = r + h * 32;
    bf16x8 v = *(const bf16x8*)(s + (size_t)row * EE + cc * 8);
    int sc = cc ^ (row & 7);
    *(bf16x8*)(&t[row * 64 + sc * 8]) = v;
  }
  __syncthreads();
  bf16* d = dst + ((size_t)b * EE + f0) * NN + n0;
#pragma unroll
  for (int h = 0; h < 2; h++) {
    int f = r + h * 32;    // feature within tile
    int nb = cc * 8;       // n chunk base
    bf16x8 v;
#pragma unroll
    for (int j = 0; j < 8; j++) {
      int n = nb + j;
      int sc = (f >> 3) ^ (n & 7);
      v[j] = t[n * 64 + sc * 8 + (f & 7)];
    }
    *(bf16x8*)(d + (size_t)f * NN + nb) = v;
  }
}

// ---------------- GEMM: C[M,N] = A[M,K] @ B[N,K]^T ----------------
// SPLIT: 3-product bf16 error compensation (hi*hi + hi*lo + lo*hi)
// EPI: 0 = write bf16 hi/lo pair (C0,C1), 1 = write float*cscale (C0), 2 = write bf16 (C0)
template <bool SPLIT, int EPI>
__global__ __launch_bounds__(256, 2) void k_gemm(
    const bf16* __restrict__ Ah, const bf16* __restrict__ Al,
    const bf16* __restrict__ Bh, const bf16* __restrict__ Bl,
    void* __restrict__ C0, void* __restrict__ C1,
    int Kdim, int lda, int ldb, int ldc,
    long long sA, long long sB, long long sC, float cscale) {
  constexpr int NTILES = SPLIT ? 4 : 2;
  __shared__ __align__(16) bf16 sm[NTILES * 128 * 64];
  bf16* smAh = sm;
  bf16* smBh = sm + 128 * 64;
  bf16* smAl = SPLIT ? sm + 2 * 128 * 64 : nullptr;
  bf16* smBl = SPLIT ? sm + 3 * 128 * 64 : nullptr;

  const int tid = threadIdx.x;
  const int lane = tid & 63, wid = tid >> 6;
  const int lr = lane & 15, lq = lane >> 4;
  const int wr = (wid >> 1) * 64, wc = (wid & 1) * 64;
  const long long bz = blockIdx.z;
  const int col0 = blockIdx.x * 128, row0 = blockIdx.y * 128;

  const bf16* pAh = Ah + bz * sA;
  const bf16* pBh = Bh + bz * sB;
  const bf16* pAl = SPLIT ? (Al + bz * sA) : nullptr;
  const bf16* pBl = SPLIT ? (Bl + bz * sB) : nullptr;

  f32x4 acc[4][4] = {};

  for (int kt = 0; kt < Kdim; kt += 64) {
    // ---- stage 128x64 bf16 tiles via global_load_lds, pre-swizzled source ----
    {
      int o = tid * 16;
#pragma unroll
      for (int r = 0; r < 4; r++, o += 4096) {
        int row = o >> 7;
        int c = (o & 127) ^ ((row & 7) << 4);  // inverse swizzle on source
        gld16((const char*)(pAh + (size_t)(row0 + row) * lda + kt) + c, (char*)smAh + o);
        gld16((const char*)(pBh + (size_t)(col0 + row) * ldb + kt) + c, (char*)smBh + o);
        if constexpr (SPLIT) {
          gld16((const char*)(pAl + (size_t)(row0 + row) * lda + kt) + c, (char*)smAl + o);
          gld16((const char*)(pBl + (size_t)(col0 + row) * ldb + kt) + c, (char*)smBl + o);
        }
      }
    }
    __syncthreads();
#pragma unroll
    for (int kk = 0; kk < 2; kk++) {
      bf16x8 ah[4], bh[4], al[4], bl[4];
#pragma unroll
      for (int i = 0; i < 4; i++) {
        int ar = wr + i * 16 + lr;
        int ao = ar * 128 + ((kk * 64 + lq * 16) ^ ((ar & 7) << 4));
        ah[i] = *(const bf16x8*)((const char*)smAh + ao);
        int br = wc + i * 16 + lr;
        int bo = br * 128 + ((kk * 64 + lq * 16) ^ ((br & 7) << 4));
        bh[i] = *(const bf16x8*)((const char*)smBh + bo);
        if constexpr (SPLIT) {
          al[i] = *(const bf16x8*)((const char*)smAl + ao);
          bl[i] = *(const bf16x8*)((const char*)smBl + bo);
        }
      }
#pragma unroll
      for (int i = 0; i < 4; i++)
#pragma unroll
        for (int j = 0; j < 4; j++) {
          acc[i][j] = __builtin_amdgcn_mfma_f32_16x16x32_bf16(ah[i], bh[j], acc[i][j], 0, 0, 0);
          if constexpr (SPLIT) {
            acc[i][j] = __builtin_amdgcn_mfma_f32_16x16x32_bf16(ah[i], bl[j], acc[i][j], 0, 0, 0);
            acc[i][j] = __builtin_amdgcn_mfma_f32_16x16x32_bf16(al[i], bh[j], acc[i][j], 0, 0, 0);
          }
        }
    }
    __syncthreads();
  }

  // ---- epilogue: C row = (lane>>4)*4 + reg, col = lane&15 (verified layout) ----
#pragma unroll
  for (int i = 0; i < 4; i++) {
#pragma unroll
    for (int j2 = 0; j2 < 4; j2++) {
      f32x4 v = acc[i][j2];
#pragma unroll
      for (int j = 0; j < 4; j++) {
        size_t r = (size_t)(row0 + wr + i * 16 + lq * 4 + j);
        size_t c = (size_t)(col0 + wc + j2 * 16 + lr);
        size_t idx = r * (size_t)ldc + c;
        float val = v[j] * cscale;
        if constexpr (EPI == 0) {
          bf16* Chp = (bf16*)C0 + bz * sC;
          bf16* Clp = (bf16*)C1 + bz * sC;
          bf16 h = (bf16)val;
          Chp[idx] = h;
          Clp[idx] = (bf16)(val - (float)h);
        } else if constexpr (EPI == 1) {
          float* Cp = (float*)C0 + bz * sC;
          Cp[idx] = val;
        } else {
          bf16* Cp = (bf16*)C0 + bz * sC;
          Cp[idx] = (bf16)val;
        }
      }
    }
  }
}

// ---------------- row softmax: S[row][0..N) fp32 -> P bf16 ----------------
__global__ __launch_bounds__(256) void k_softmax(const float* __restrict__ S,
                                                 bf16* __restrict__ P) {
  size_t row = blockIdx.x;
  const float4* s = (const float4*)(S + row * NN);
  int tid = threadIdx.x;
  int wid = tid >> 6, lane = tid & 63;
  float4 v0 = s[tid * 2], v1 = s[tid * 2 + 1];
  float vv[8] = {v0.x, v0.y, v0.z, v0.w, v1.x, v1.y, v1.z, v1.w};
  float m = vv[0];
#pragma unroll
  for (int j = 1; j < 8; j++) m = fmaxf(m, vv[j]);
#pragma unroll
  for (int d = 1; d < 64; d <<= 1) m = fmaxf(m, __shfl_xor(m, d));
  __shared__ float red[8];
  if (lane == 0) red[wid] = m;
  __syncthreads();
  m = fmaxf(fmaxf(red[0], red[1]), fmaxf(red[2], red[3]));
  float e[8];
  float ssum = 0.f;
#pragma unroll
  for (int j = 0; j < 8; j++) { e[j] = __expf(vv[j] - m); ssum += e[j]; }
#pragma unroll
  for (int d = 1; d < 64; d <<= 1) ssum += __shfl_xor(ssum, d);
  if (lane == 0) red[4 + wid] = ssum;
  __syncthreads();
  ssum = red[4] + red[5] + red[6] + red[7];
  float inv = 1.0f / ssum;
  bf16x8 p;
#pragma unroll
  for (int j = 0; j < 8; j++) p[j] = (bf16)(e[j] * inv);
  *(bf16x8*)(P + row * NN + tid * 8) = p;
}

// ---------------- host ----------------
extern "C" void kernel_launch(void* const* d_in, const int* in_sizes, int n_in,
                              void* d_out, int out_size, void* d_ws, size_t ws_size,
                              hipStream_t stream) {
  const float* x  = (const float*)d_in[0];
  const float* Wq = (const float*)d_in[1];
  const float* Wk = (const float*)d_in[2];
  const float* Wv = (const float*)d_in[3];
  const float* Wo = (const float*)d_in[4];
  float* out = (float*)d_out;
  char* ws = (char*)d_ws;

  const size_t szXE = (size_t)MM * EE * 2;  // bf16 [M][E]
  const size_t szW  = (size_t)EE * EE * 2;  // bf16 [E][E]

  bf16* xhi = (bf16*)(ws);
  bf16* xlo = (bf16*)(ws + szXE);
  char* wb  = ws + 2 * szXE;
  bf16* wqh = (bf16*)(wb);
  bf16* wql = (bf16*)(wb + szW);
  bf16* wkh = (bf16*)(wb + 2 * szW);
  bf16* wkl = (bf16*)(wb + 3 * szW);
  bf16* wvb = (bf16*)(wb + 4 * szW);
  bf16* wob = (bf16*)(wb + 5 * szW);
  char* base2 = wb + 6 * szW;
  bf16* Qh = (bf16*)(base2);
  bf16* Ql = (bf16*)(base2 + szXE);
  bf16* Kh = (bf16*)(base2 + 2 * szXE);
  bf16* Kl = (bf16*)(base2 + 3 * szXE);
  bf16* Vb = (bf16*)(base2 + 4 * szXE);
  bf16* Vt = (bf16*)(base2 + 5 * szXE);
  bf16* Ao = (bf16*)(base2 + 6 * szXE);
  char* base3 = base2 + 7 * szXE;

  const size_t szS1 = (size_t)NN * NN * 4;  // 16.78 MB
  const size_t szP1 = (size_t)NN * NN * 2;  // 8.39 MB
  const size_t need_full = (size_t)(base3 - ws) + BB * szS1 + BB * szP1;
  const bool full = ws_size >= need_full;

  float* S = (float*)base3;
  bf16*  P = full ? (bf16*)(base3 + BB * szS1) : (bf16*)Vb;  // per-batch: reuse Vb (dead after transpose)

  // conversions
  k_split<<<2048, 256, 0, stream>>>((const float4*)x, (bf16x4*)xhi, (bf16x4*)xlo, MM * EE / 4);
  k_split<<<64, 256, 0, stream>>>((const float4*)Wq, (bf16x4*)wqh, (bf16x4*)wql, EE * EE / 4);
  k_split<<<64, 256, 0, stream>>>((const float4*)Wk, (bf16x4*)wkh, (bf16x4*)wkl, EE * EE / 4);
  k_cvt<<<64, 256, 0, stream>>>((const float4*)Wv, (bf16x4*)wvb, EE * EE / 4);
  k_cvt<<<64, 256, 0, stream>>>((const float4*)Wo, (bf16x4*)wob, EE * EE / 4);

  // projections (grid.x = N-tiles so consecutive blocks reuse the A row-panel in L2)
  dim3 gproj(EE / 128, MM / 128, 1);  // (6, 128)
  k_gemm<true, 0><<<gproj, 256, 0, stream>>>(xhi, xlo, wqh, wql, Qh, Ql, EE, EE, EE, EE, 0, 0, 0, 1.0f);
  k_gemm<true, 0><<<gproj, 256, 0, stream>>>(xhi, xlo, wkh, wkl, Kh, Kl, EE, EE, EE, EE, 0, 0, 0, 1.0f);
  k_gemm<false, 2><<<gproj, 256, 0, stream>>>(xhi, nullptr, wvb, nullptr, Vb, nullptr, EE, EE, EE, EE, 0, 0, 0, 1.0f);
  k_transpose<<<dim3(NN / 64, EE / 64, BB), 256, 0, stream>>>(Vb, Vt);

  const long long sQ = (long long)NN * EE;
  if (full) {
    k_gemm<true, 1><<<dim3(NN / 128, NN / 128, BB), 256, 0, stream>>>(
        Qh, Ql, Kh, Kl, S, nullptr, EE, EE, EE, NN, sQ, sQ, (long long)NN * NN, 8.0f);
    k_softmax<<<MM, 256, 0, stream>>>(S, P);
    k_gemm<false, 2><<<dim3(EE / 128, NN / 128, BB), 256, 0, stream>>>(
        P, nullptr, Vt, nullptr, Ao, nullptr, NN, NN, NN, EE, (long long)NN * NN, sQ, sQ, 1.0f);
  } else {
    for (int b = 0; b < BB; b++) {
      k_gemm<true, 1><<<dim3(NN / 128, NN / 128, 1), 256, 0, stream>>>(
          Qh + b * sQ, Ql + b * sQ, Kh + b * sQ, Kl + b * sQ, S, nullptr, EE, EE, EE, NN, 0, 0, 0, 8.0f);
      k_softmax<<<NN, 256, 0, stream>>>(S, P);
      k_gemm<false, 2><<<dim3(EE / 128, NN / 128, 1), 256, 0, stream>>>(
          P, nullptr, Vt + b * sQ, nullptr, Ao + b * sQ, nullptr, NN, NN, NN, EE, 0, 0, 0, 1.0f);
    }
  }

  // output projection -> fp32 d_out
  k_gemm<false, 1><<<gproj, 256, 0, stream>>>(Ao, nullptr, wob, nullptr, out, nullptr, EE, EE, EE, EE, 0, 0, 0, 1.0f);
}

// Round 2
// 448.836 us; speedup vs baseline: 1.7764x; 1.7764x over previous
//
#include <hip/hip_runtime.h>
#include <stdint.h>

typedef __bf16 bf16;
typedef __bf16 bf16x4 __attribute__((ext_vector_type(4)));
typedef __bf16 bf16x8 __attribute__((ext_vector_type(8)));
typedef float  f32x4  __attribute__((ext_vector_type(4)));

constexpr int BB = 8;
constexpr int NN = 2048;
constexpr int EE = 768;
constexpr int MM = BB * NN;   // 16384
constexpr int E2 = 2 * EE;    // 1536 (Q|K merged)

typedef const __attribute__((address_space(1))) void* as1_cvp;
typedef __attribute__((address_space(3))) void* as3_vp;

static __device__ __forceinline__ void gld16(const void* g, void* l) {
  __builtin_amdgcn_global_load_lds((as1_cvp)g, (as3_vp)l, 16, 0, 0);
}

// ---------------- x -> bf16 hi/lo split ----------------
__global__ __launch_bounds__(256) void k_splitx(const float4* __restrict__ x,
                                                bf16x4* __restrict__ hi,
                                                bf16x4* __restrict__ lo, int n4) {
  int i = blockIdx.x * 256 + threadIdx.x;
  int st = gridDim.x * 256;
  for (; i < n4; i += st) {
    float4 v = x[i];
    bf16x4 h, l;
    h[0] = (bf16)v.x; l[0] = (bf16)(v.x - (float)h[0]);
    h[1] = (bf16)v.y; l[1] = (bf16)(v.y - (float)h[1]);
    h[2] = (bf16)v.z; l[2] = (bf16)(v.z - (float)h[2]);
    h[3] = (bf16)v.w; l[3] = (bf16)(v.w - (float)h[3]);
    hi[i] = h; lo[i] = l;
  }
}

// ---------------- weight prep: Wq,Wk -> split into [Wq;Wk]; Wv,Wo -> bf16 ----------------
__global__ __launch_bounds__(256) void k_wprep(const float4* __restrict__ wq,
                                               const float4* __restrict__ wk,
                                               const float4* __restrict__ wv,
                                               const float4* __restrict__ wo,
                                               bf16x4* __restrict__ qkh, bf16x4* __restrict__ qkl,
                                               bf16x4* __restrict__ vb,  bf16x4* __restrict__ ob) {
  const int n4 = EE * EE / 4;  // 147456
  int sel = blockIdx.y;
  int i = blockIdx.x * 256 + threadIdx.x;
  int st = gridDim.x * 256;
  for (; i < n4; i += st) {
    if (sel <= 1) {
      float4 v = sel == 0 ? wq[i] : wk[i];
      bf16x4 h, l;
      h[0] = (bf16)v.x; l[0] = (bf16)(v.x - (float)h[0]);
      h[1] = (bf16)v.y; l[1] = (bf16)(v.y - (float)h[1]);
      h[2] = (bf16)v.z; l[2] = (bf16)(v.z - (float)h[2]);
      h[3] = (bf16)v.w; l[3] = (bf16)(v.w - (float)h[3]);
      int o = i + sel * n4;
      qkh[o] = h; qkl[o] = l;
    } else {
      float4 v = sel == 2 ? wv[i] : wo[i];
      bf16x4 h;
      h[0] = (bf16)v.x; h[1] = (bf16)v.y; h[2] = (bf16)v.z; h[3] = (bf16)v.w;
      if (sel == 2) vb[i] = h; else ob[i] = h;
    }
  }
}

// ---------------- GEMM: C[M,N] = A[M,K] @ B[N,K]^T ----------------
// SPLIT: 3-product bf16 error compensation (hi*hi + hi*lo + lo*hi)
// EPI: 0 = bf16 hi/lo pair (C0,C1); 1 = float*cscale (C0); 2 = bf16 (C0);
//      3 = bf16 transposed V write: C0 = Vt[B][EE][NN], r -> (b,n), c -> f
template <bool SPLIT, int EPI>
__global__ __launch_bounds__(256, 2) void k_gemm(
    const bf16* __restrict__ Ah, const bf16* __restrict__ Al,
    const bf16* __restrict__ Bh, const bf16* __restrict__ Bl,
    void* __restrict__ C0, void* __restrict__ C1,
    int Kdim, int lda, int ldb, int ldc,
    long long sA, long long sB, long long sC, float cscale) {
  constexpr int NTILES = SPLIT ? 4 : 2;
  __shared__ __align__(16) bf16 sm[NTILES * 128 * 64];
  bf16* smAh = sm;
  bf16* smBh = sm + 128 * 64;
  bf16* smAl = SPLIT ? sm + 2 * 128 * 64 : nullptr;
  bf16* smBl = SPLIT ? sm + 3 * 128 * 64 : nullptr;

  const int tid = threadIdx.x;
  const int lane = tid & 63, wid = tid >> 6;
  const int lr = lane & 15, lq = lane >> 4;
  const int wr = (wid >> 1) * 64, wc = (wid & 1) * 64;
  const long long bz = blockIdx.z;
  const int col0 = blockIdx.x * 128, row0 = blockIdx.y * 128;

  const bf16* pAh = Ah + bz * sA;
  const bf16* pBh = Bh + bz * sB;
  const bf16* pAl = SPLIT ? (Al + bz * sA) : nullptr;
  const bf16* pBl = SPLIT ? (Bl + bz * sB) : nullptr;

  f32x4 acc[4][4] = {};

  for (int kt = 0; kt < Kdim; kt += 64) {
    {
      int o = tid * 16;
#pragma unroll
      for (int r = 0; r < 4; r++, o += 4096) {
        int row = o >> 7;
        int c = (o & 127) ^ ((row & 7) << 4);  // inverse swizzle on source
        gld16((const char*)(pAh + (size_t)(row0 + row) * lda + kt) + c, (char*)smAh + o);
        gld16((const char*)(pBh + (size_t)(col0 + row) * ldb + kt) + c, (char*)smBh + o);
        if constexpr (SPLIT) {
          gld16((const char*)(pAl + (size_t)(row0 + row) * lda + kt) + c, (char*)smAl + o);
          gld16((const char*)(pBl + (size_t)(col0 + row) * ldb + kt) + c, (char*)smBl + o);
        }
      }
    }
    __syncthreads();
#pragma unroll
    for (int kk = 0; kk < 2; kk++) {
      bf16x8 ah[4], bh[4], al[4], bl[4];
#pragma unroll
      for (int i = 0; i < 4; i++) {
        int ar = wr + i * 16 + lr;
        int ao = ar * 128 + ((kk * 64 + lq * 16) ^ ((ar & 7) << 4));
        ah[i] = *(const bf16x8*)((const char*)smAh + ao);
        int br = wc + i * 16 + lr;
        int bo = br * 128 + ((kk * 64 + lq * 16) ^ ((br & 7) << 4));
        bh[i] = *(const bf16x8*)((const char*)smBh + bo);
        if constexpr (SPLIT) {
          al[i] = *(const bf16x8*)((const char*)smAl + ao);
          bl[i] = *(const bf16x8*)((const char*)smBl + bo);
        }
      }
#pragma unroll
      for (int i = 0; i < 4; i++)
#pragma unroll
        for (int j = 0; j < 4; j++) {
          acc[i][j] = __builtin_amdgcn_mfma_f32_16x16x32_bf16(ah[i], bh[j], acc[i][j], 0, 0, 0);
          if constexpr (SPLIT) {
            acc[i][j] = __builtin_amdgcn_mfma_f32_16x16x32_bf16(ah[i], bl[j], acc[i][j], 0, 0, 0);
            acc[i][j] = __builtin_amdgcn_mfma_f32_16x16x32_bf16(al[i], bh[j], acc[i][j], 0, 0, 0);
          }
        }
    }
    __syncthreads();
  }

  // C/D layout: row = (lane>>4)*4 + reg, col = lane&15 (verified)
#pragma unroll
  for (int i = 0; i < 4; i++) {
#pragma unroll
    for (int j2 = 0; j2 < 4; j2++) {
      f32x4 v = acc[i][j2];
      if constexpr (EPI == 3) {
        int r0 = row0 + wr + i * 16 + lq * 4;
        int c = col0 + wc + j2 * 16 + lr;
        int b = r0 >> 11, n0 = r0 & 2047;
        bf16x4 t;
#pragma unroll
        for (int j = 0; j < 4; j++) t[j] = (bf16)(v[j] * cscale);
        *(bf16x4*)((bf16*)C0 + ((size_t)b * EE + c) * NN + n0) = t;
      } else {
#pragma unroll
        for (int j = 0; j < 4; j++) {
          size_t r = (size_t)(row0 + wr + i * 16 + lq * 4 + j);
          size_t c = (size_t)(col0 + wc + j2 * 16 + lr);
          size_t idx = r * (size_t)ldc + c;
          float val = v[j] * cscale;
          if constexpr (EPI == 0) {
            bf16* Chp = (bf16*)C0 + bz * sC;
            bf16* Clp = (bf16*)C1 + bz * sC;
            bf16 h = (bf16)val;
            Chp[idx] = h;
            Clp[idx] = (bf16)(val - (float)h);
          } else if constexpr (EPI == 1) {
            float* Cp = (float*)C0 + bz * sC;
            Cp[idx] = val;
          } else {
            bf16* Cp = (bf16*)C0 + bz * sC;
            Cp[idx] = (bf16)val;
          }
        }
      }
    }
  }
}

// ---------------- row softmax in-place: S row fp32 -> P bf16 in first half of same row ----------------
__global__ __launch_bounds__(256) void k_softmax(float* __restrict__ S) {
  size_t row = blockIdx.x;
  float* srow = S + row * (size_t)NN;
  int tid = threadIdx.x;
  int wid = tid >> 6, lane = tid & 63;
  const float4* s4 = (const float4*)srow;
  float4 v0 = s4[tid * 2], v1 = s4[tid * 2 + 1];
  float vv[8] = {v0.x, v0.y, v0.z, v0.w, v1.x, v1.y, v1.z, v1.w};
  float m = vv[0];
#pragma unroll
  for (int j = 1; j < 8; j++) m = fmaxf(m, vv[j]);
#pragma unroll
  for (int d = 1; d < 64; d <<= 1) m = fmaxf(m, __shfl_xor(m, d));
  __shared__ float red[8];
  if (lane == 0) red[wid] = m;
  __syncthreads();
  m = fmaxf(fmaxf(red[0], red[1]), fmaxf(red[2], red[3]));
  float e[8];
  float ssum = 0.f;
#pragma unroll
  for (int j = 0; j < 8; j++) { e[j] = __expf(vv[j] - m); ssum += e[j]; }
#pragma unroll
  for (int d = 1; d < 64; d <<= 1) ssum += __shfl_xor(ssum, d);
  if (lane == 0) red[4 + wid] = ssum;
  __syncthreads();
  ssum = red[4] + red[5] + red[6] + red[7];
  float inv = 1.0f / ssum;
  bf16x8 p;
#pragma unroll
  for (int j = 0; j < 8; j++) p[j] = (bf16)(e[j] * inv);
  // all loads of this row happened before the barriers above -> in-place safe
  *(bf16x8*)((bf16*)srow + tid * 8) = p;
}

// ---------------- host ----------------
extern "C" void kernel_launch(void* const* d_in, const int* in_sizes, int n_in,
                              void* d_out, int out_size, void* d_ws, size_t ws_size,
                              hipStream_t stream) {
  const float* x  = (const float*)d_in[0];
  const float* Wq = (const float*)d_in[1];
  const float* Wk = (const float*)d_in[2];
  const float* Wv = (const float*)d_in[3];
  const float* Wo = (const float*)d_in[4];
  float* out = (float*)d_out;
  char* ws = (char*)d_ws;

  const size_t szXE = (size_t)MM * EE * 2;      // 25.17 MB  bf16 [M][E]
  const size_t szWb = (size_t)EE * EE * 2;      // 1.18 MB
  const size_t szQKh = (size_t)MM * E2 * 2;     // 50.33 MB  bf16 [M][1536]
  const size_t szS1 = (size_t)NN * NN * 4;      // 16.78 MB  fp32 [N][N]

  bf16* xhi = (bf16*)(ws);
  bf16* xlo = (bf16*)(ws + szXE);
  char* wb  = ws + 2 * szXE;
  bf16* wqkh = (bf16*)(wb);                 // [1536][768] hi
  bf16* wqkl = (bf16*)(wb + 2 * szWb);      // [1536][768] lo
  bf16* wvb  = (bf16*)(wb + 4 * szWb);
  bf16* wob  = (bf16*)(wb + 5 * szWb);
  char* qkb = wb + 6 * szWb;
  bf16* QKh = (bf16*)(qkb);                 // [M][1536] hi (cols 0..767 = Q, 768.. = K)
  bf16* QKl = (bf16*)(qkb + szQKh);
  bf16* Vt  = (bf16*)(qkb + 2 * szQKh);     // [B][768][2048]
  char* Sb  = qkb + 2 * szQKh + szXE;
  float* S  = (float*)Sb;                   // [G][N][N] fp32; P bf16 lives in first half of each row
  bf16* Ao  = (bf16*)ws;                    // overlay x (dead after projections)

  size_t oS = (size_t)(Sb - ws);
  size_t avail = ws_size > oS ? ws_size - oS : 0;
  int G = 8;
  while (G > 1 && (size_t)G * szS1 > avail) G >>= 1;

  // conversions
  k_splitx<<<2048, 256, 0, stream>>>((const float4*)x, (bf16x4*)xhi, (bf16x4*)xlo, MM * EE / 4);
  k_wprep<<<dim3(144, 4), 256, 0, stream>>>((const float4*)Wq, (const float4*)Wk,
                                            (const float4*)Wv, (const float4*)Wo,
                                            (bf16x4*)wqkh, (bf16x4*)wqkl, (bf16x4*)wvb, (bf16x4*)wob);

  // merged Q|K projection: C [M][1536] hi/lo
  k_gemm<true, 0><<<dim3(E2 / 128, MM / 128, 1), 256, 0, stream>>>(
      xhi, xlo, wqkh, wqkl, QKh, QKl, EE, EE, EE, E2, 0, 0, 0, 1.0f);
  // V projection, written transposed into Vt
  k_gemm<false, 3><<<dim3(EE / 128, MM / 128, 1), 256, 0, stream>>>(
      xhi, nullptr, wvb, nullptr, Vt, nullptr, EE, EE, EE, 0, 0, 0, 0, 1.0f);

  const long long sQK = (long long)NN * E2;  // per-batch stride in QKh/QKl
  for (int g = 0; g < BB; g += G) {
    const bf16* Qh = QKh + (size_t)g * NN * E2;
    const bf16* Ql = QKl + (size_t)g * NN * E2;
    // S = 8 * Q @ K^T   (both split)
    k_gemm<true, 1><<<dim3(NN / 128, NN / 128, G), 256, 0, stream>>>(
        Qh, Ql, Qh + EE, Ql + EE, S, nullptr, EE, E2, E2, NN,
        sQK, sQK, (long long)NN * NN, 8.0f);
    // softmax rows, P bf16 in-place
    k_softmax<<<G * NN, 256, 0, stream>>>(S);
    // Ao = P @ V   (A = P strided inside S)
    k_gemm<false, 2><<<dim3(EE / 128, NN / 128, G), 256, 0, stream>>>(
        (const bf16*)S, nullptr, Vt + (size_t)g * EE * NN, nullptr,
        Ao + (size_t)g * NN * EE, nullptr, NN, 2 * NN, NN, EE,
        2LL * NN * NN, (long long)EE * NN, (long long)NN * EE, 1.0f);
  }

  // output projection -> fp32 d_out
  k_gemm<false, 1><<<dim3(EE / 128, MM / 128, 1), 256, 0, stream>>>(
      Ao, nullptr, wob, nullptr, out, nullptr, EE, EE, EE, EE, 0, 0, 0, 1.0f);
}